// Round 3
// baseline (59.627 us; speedup 1.0000x reference)
//
#include <hip/hip_runtime.h>

// Problem constants (fixed by the reference's setup_inputs)
#define IN_F   256
#define N_ASS  4096
#define OUT_F  256
#define BATCH  128
#define ASS0   256      // first associative node index
#define OUT0   4352     // first output node index (IN_F + N_ASS)
#define SPLITK 32       // GEMM2 split-K factor

// Workspace layout (fp32):
//   W1d : [N_ASS][IN_F]   @ 0                       (4 MB)  dense input->assoc weights
//   W2d : [OUT_F][N_ASS]  @ N_ASS*IN_F              (4 MB)  dense assoc->output weights
//   acc : [BATCH][N_ASS]  @ N_ASS*IN_F+OUT_F*N_ASS  (2 MB)  hop-1 activations

// Zero W (8 MB in d_ws) and out (128 KB) in one kernel.
__global__ void init_kernel(float4* __restrict__ w, int n4w,
                            float4* __restrict__ o, int n4o) {
    int i = blockIdx.x * blockDim.x + threadIdx.x;
    const float4 z = make_float4(0.f, 0.f, 0.f, 0.f);
    if (i < n4w) w[i] = z;
    else if (i - n4w < n4o) o[i - n4w] = z;
}

// One kernel for both edge scatters. (src,dst) pairs are unique -> plain stores.
__global__ void scatter_both(const int* __restrict__ src1, const int* __restrict__ dst1,
                             const float* __restrict__ w1, int E1,
                             const int* __restrict__ src2, const int* __restrict__ dst2,
                             const float* __restrict__ w2, int E2,
                             float* __restrict__ W1d, float* __restrict__ W2d) {
    int e = blockIdx.x * blockDim.x + threadIdx.x;
    if (e < E1) {
        W1d[(dst1[e] - ASS0) * IN_F + src1[e]] = w1[e];
    } else if (e - E1 < E2) {
        int i = e - E1;
        int d = dst2[i];
        if (d >= OUT0) {   // only edges into output nodes affect the result
            W2d[(d - OUT0) * N_ASS + (src2[i] - ASS0)] = w2[i];
        }
    }
}

// C[M][N] (+)= A[M][Kchunk] * B[N][Kchunk]^T  (row-major, "NT" dot-product GEMM)
// BN=64, BM in {32,64}, 256 threads, micro-tile (BM/16) x 4.
// ATOMIC: accumulate into C with atomicAdd (split-K); else plain store.
template<int BM, bool ATOMIC>
__global__ __launch_bounds__(256) void gemm_nt(const float* __restrict__ A,
                                               const float* __restrict__ B,
                                               float* __restrict__ C,
                                               int M, int N, int K, int kChunk) {
    constexpr int BN = 64, BK = 16;
    constexpr int TM = BM / 16;          // rows per thread
    __shared__ __align__(16) float As[BK][BM + 4];
    __shared__ __align__(16) float Bs[BK][BN + 4];

    const int tid = threadIdx.x;
    const int tx = tid & 15;             // N direction
    const int ty = tid >> 4;             // M direction
    const int m0 = blockIdx.x * BM;
    const int n0 = blockIdx.y * BN;
    const int kBeg = blockIdx.z * kChunk;
    const int kEnd = kBeg + kChunk;

    const int lr = tid >> 2;             // loader row 0..63
    const int lc = (tid & 3) * 4;        // loader k-offset
    const bool hasA = (lr < BM);

    float acc[TM][4] = {};

    for (int k0 = kBeg; k0 < kEnd; k0 += BK) {
        float4 av, bv;
        if (hasA) av = *(const float4*)(A + (size_t)(m0 + lr) * K + k0 + lc);
        bv = *(const float4*)(B + (size_t)(n0 + lr) * K + k0 + lc);
        __syncthreads();   // protect previous iteration's LDS reads
        if (hasA) {
            As[lc + 0][lr] = av.x; As[lc + 1][lr] = av.y;
            As[lc + 2][lr] = av.z; As[lc + 3][lr] = av.w;
        }
        Bs[lc + 0][lr] = bv.x; Bs[lc + 1][lr] = bv.y;
        Bs[lc + 2][lr] = bv.z; Bs[lc + 3][lr] = bv.w;
        __syncthreads();

        #pragma unroll
        for (int k = 0; k < BK; ++k) {
            float4 b4 = *(const float4*)&Bs[k][tx * 4];
            float b[4] = {b4.x, b4.y, b4.z, b4.w};
            float a[TM];
            if constexpr (TM == 4) {
                float4 a4 = *(const float4*)&As[k][ty * 4];
                a[0] = a4.x; a[1] = a4.y; a[2] = a4.z; a[3] = a4.w;
            } else {
                float2 a2 = *(const float2*)&As[k][ty * 2];
                a[0] = a2.x; a[1] = a2.y;
            }
            #pragma unroll
            for (int i = 0; i < TM; ++i)
                #pragma unroll
                for (int j = 0; j < 4; ++j)
                    acc[i][j] = fmaf(a[i], b[j], acc[i][j]);
        }
    }

    #pragma unroll
    for (int i = 0; i < TM; ++i) {
        const int m = m0 + ty * TM + i;
        if (ATOMIC) {
            #pragma unroll
            for (int j = 0; j < 4; ++j)
                atomicAdd(&C[(size_t)m * N + n0 + tx * 4 + j], acc[i][j]);
        } else {
            float4 v = make_float4(acc[i][0], acc[i][1], acc[i][2], acc[i][3]);
            *(float4*)&C[(size_t)m * N + n0 + tx * 4] = v;
        }
    }
}

extern "C" void kernel_launch(void* const* d_in, const int* in_sizes, int n_in,
                              void* d_out, int out_size, void* d_ws, size_t ws_size,
                              hipStream_t stream) {
    const float* x      = (const float*)d_in[0];   // [BATCH][IN_F]
    const float* w_in   = (const float*)d_in[1];   // [E_in]
    const float* w_ass  = (const float*)d_in[2];   // [E_ass]
    const int*   in_src = (const int*)d_in[3];
    const int*   in_dst = (const int*)d_in[4];
    const int*   a_src  = (const int*)d_in[5];
    const int*   a_dst  = (const int*)d_in[6];
    const int E_in  = in_sizes[3];
    const int E_ass = in_sizes[5];

    float* W1d = (float*)d_ws;                       // [N_ASS][IN_F]
    float* W2d = W1d + (size_t)N_ASS * IN_F;         // [OUT_F][N_ASS]
    float* acc = W2d + (size_t)OUT_F * N_ASS;        // [BATCH][N_ASS]
    float* out = (float*)d_out;                      // [BATCH][OUT_F]

    // 1) zero dense weights (8 MB) + out (128 KB)
    const int n4w = (N_ASS * IN_F + OUT_F * N_ASS) / 4;
    const int n4o = (BATCH * OUT_F) / 4;
    init_kernel<<<(n4w + n4o + 255) / 256, 256, 0, stream>>>((float4*)d_ws, n4w,
                                                             (float4*)d_out, n4o);

    // 2) both scatters
    const int Etot = E_in + E_ass;
    scatter_both<<<(Etot + 255) / 256, 256, 0, stream>>>(in_src, in_dst, w_in, E_in,
                                                         a_src, a_dst, w_ass, E_ass,
                                                         W1d, W2d);

    // 3) GEMM1: acc[128][4096] = x[128][256] * W1d[4096][256]^T   (256 blocks)
    dim3 g1(BATCH / 32, N_ASS / 64, 1);
    gemm_nt<32, false><<<g1, 256, 0, stream>>>(x, W1d, acc, BATCH, N_ASS, IN_F, IN_F);

    // 4) GEMM2: out += acc * W2d^T, split-K=32, atomic into zeroed out (256 blocks)
    dim3 g2(BATCH / 64, OUT_F / 64, SPLITK);
    gemm_nt<64, true><<<g2, 256, 0, stream>>>(acc, W2d, out, BATCH, OUT_F, N_ASS, N_ASS / SPLITK);
}